// Round 1
// baseline (640.196 us; speedup 1.0000x reference)
//
#include <hip/hip_runtime.h>

// Problem dims (LRNetLinear): out = B x O, x = B x I, weights O x I
#define I_DIM 4096
#define O_DIM 4096
#define B_DIM 4096

typedef __bf16 bf16;
typedef __attribute__((ext_vector_type(8))) __bf16 bf16x8;
typedef __attribute__((ext_vector_type(4))) float f32x4;

// fp32 -> bf16 bits, round-to-nearest-even
__device__ inline unsigned short f2bf_bits(float f) {
    unsigned u = __builtin_bit_cast(unsigned, f);
    unsigned r = 0x7fffu + ((u >> 16) & 1u);
    return (unsigned short)((u + r) >> 16);
}

// ---------------------------------------------------------------------------
// Prep 1: x -> bf16(x), bf16(x*x)
// ---------------------------------------------------------------------------
__global__ void prep_x(const float4* __restrict__ x,
                       ushort4* __restrict__ xb,
                       ushort4* __restrict__ x2b) {
    size_t i = (size_t)blockIdx.x * blockDim.x + threadIdx.x;
    float4 v = x[i];
    ushort4 o1, o2;
    o1.x = f2bf_bits(v.x); o1.y = f2bf_bits(v.y);
    o1.z = f2bf_bits(v.z); o1.w = f2bf_bits(v.w);
    o2.x = f2bf_bits(v.x * v.x); o2.y = f2bf_bits(v.y * v.y);
    o2.z = f2bf_bits(v.z * v.z); o2.w = f2bf_bits(v.w * v.w);
    xb[i] = o1;
    x2b[i] = o2;
}

// ---------------------------------------------------------------------------
// Prep 2: (theta_neg, theta_pos, scales_exp) -> bf16 w_mean, w_var
// ---------------------------------------------------------------------------
__device__ inline void lr_wmv(float tn, float tp, float s,
                              unsigned short& wm, unsigned short& wv) {
    float m = fmaxf(fmaxf(tn, tp), 0.0f);
    float en = __expf(tn - m);
    float ez = __expf(-m);
    float ep = __expf(tp - m);
    float inv = 1.0f / (en + ez + ep);
    float pn = en * inv, pp = ep * inv;
    float d = pp - pn;
    wm = f2bf_bits(d * s);
    wv = f2bf_bits((pp + pn - d * d) * (s * s));
}

__global__ void prep_weights(const float4* __restrict__ tn,
                             const float4* __restrict__ tp,
                             const float4* __restrict__ sc,
                             ushort4* __restrict__ wm,
                             ushort4* __restrict__ wv) {
    size_t i = (size_t)blockIdx.x * blockDim.x + threadIdx.x;
    float4 a = tn[i];
    float4 b = tp[i];
    float4 s = sc[i];
    ushort4 om, ov;
    lr_wmv(a.x, b.x, s.x, om.x, ov.x);
    lr_wmv(a.y, b.y, s.y, om.y, ov.y);
    lr_wmv(a.z, b.z, s.z, om.z, ov.z);
    lr_wmv(a.w, b.w, s.w, om.w, ov.w);
    wm[i] = om;
    wv[i] = ov;
}

// ---------------------------------------------------------------------------
// Fused dual GEMM: mu = Xb . Wm^T ; var = X2b . Wv^T ; out = mu + sqrt(var)*eps
// m97 structure: 128x128 block tile, BK=32, global_load_lds(16B) staging,
// 4 waves each computing a 64x64 sub-tile via 4x4 blocks of 16x16x32 MFMA,
// TWO accumulator sets (mu, var).
// ---------------------------------------------------------------------------
#define BM 128
#define BN 128
#define BK 32

__device__ inline void gl_lds16(const bf16* g, bf16* l) {
    __builtin_amdgcn_global_load_lds(
        (const __attribute__((address_space(1))) unsigned int*)g,
        (__attribute__((address_space(3))) unsigned int*)l,
        16, 0, 0);
}

__global__ __launch_bounds__(256, 2)
void fused_dual_gemm(const bf16* __restrict__ Xb, const bf16* __restrict__ X2b,
                     const bf16* __restrict__ Wm, const bf16* __restrict__ Wv,
                     const float* __restrict__ eps, float* __restrict__ out) {
    __shared__ bf16 sX[BM * BK];
    __shared__ bf16 sX2[BM * BK];
    __shared__ bf16 sWm[BN * BK];
    __shared__ bf16 sWv[BN * BK];

    const int tid  = threadIdx.x;
    const int lane = tid & 63;
    const int wave = tid >> 6;

    const int bm = blockIdx.y * BM;   // M (token) tile origin
    const int bn = blockIdx.x * BN;   // N (out-feature) tile origin

    // ---- staging mapping: tile is row-major [128][32] bf16 (8 KB).
    // 8 chunks of 1 KB (64 lanes x 16 B); wave w stages chunks w and w+4.
    // elem index e = chunk*512 + lane*8 -> row = e>>5, col = e&31.
    const int e0 = wave * 512 + lane * 8;
    const int e1 = e0 + 2048;
    const int r0 = e0 >> 5, c0 = e0 & 31;
    const int r1 = e1 >> 5, c1 = e1 & 31;

    const bf16* gX0  = Xb  + (size_t)(bm + r0) * I_DIM + c0;
    const bf16* gX1  = Xb  + (size_t)(bm + r1) * I_DIM + c1;
    const bf16* gX20 = X2b + (size_t)(bm + r0) * I_DIM + c0;
    const bf16* gX21 = X2b + (size_t)(bm + r1) * I_DIM + c1;
    const bf16* gWm0 = Wm  + (size_t)(bn + r0) * I_DIM + c0;
    const bf16* gWm1 = Wm  + (size_t)(bn + r1) * I_DIM + c1;
    const bf16* gWv0 = Wv  + (size_t)(bn + r0) * I_DIM + c0;
    const bf16* gWv1 = Wv  + (size_t)(bn + r1) * I_DIM + c1;

    bf16* lX0  = sX  + wave * 512;
    bf16* lX1  = sX  + wave * 512 + 2048;
    bf16* lX20 = sX2 + wave * 512;
    bf16* lX21 = sX2 + wave * 512 + 2048;
    bf16* lWm0 = sWm + wave * 512;
    bf16* lWm1 = sWm + wave * 512 + 2048;
    bf16* lWv0 = sWv + wave * 512;
    bf16* lWv1 = sWv + wave * 512 + 2048;

    // ---- fragment read offsets (16x16x32: row = lane&15, k = (lane>>4)*8)
    const int fr = lane & 15;
    const int fk = (lane >> 4) << 3;
    const int m0 = (wave >> 1) << 6;   // wave sub-tile origin in M
    const int n0 = (wave & 1) << 6;    // wave sub-tile origin in N

    f32x4 accM[4][4];
    f32x4 accV[4][4];
    const f32x4 z = {0.0f, 0.0f, 0.0f, 0.0f};
#pragma unroll
    for (int mi = 0; mi < 4; ++mi)
#pragma unroll
        for (int ni = 0; ni < 4; ++ni) { accM[mi][ni] = z; accV[mi][ni] = z; }

    for (int k0 = 0; k0 < I_DIM; k0 += BK) {
        __syncthreads();   // previous iteration's reads done before overwrite
        gl_lds16(gX0  + k0, lX0);
        gl_lds16(gX1  + k0, lX1);
        gl_lds16(gX20 + k0, lX20);
        gl_lds16(gX21 + k0, lX21);
        gl_lds16(gWm0 + k0, lWm0);
        gl_lds16(gWm1 + k0, lWm1);
        gl_lds16(gWv0 + k0, lWv0);
        gl_lds16(gWv1 + k0, lWv1);
        __syncthreads();   // staging complete (compiler drains vmcnt)

        bf16x8 ax[4], ax2[4];
#pragma unroll
        for (int mi = 0; mi < 4; ++mi) {
            const int row = m0 + mi * 16 + fr;
            ax[mi]  = *(const bf16x8*)&sX [row * BK + fk];
            ax2[mi] = *(const bf16x8*)&sX2[row * BK + fk];
        }
#pragma unroll
        for (int ni = 0; ni < 4; ++ni) {
            const int rowb = n0 + ni * 16 + fr;
            bf16x8 bm_ = *(const bf16x8*)&sWm[rowb * BK + fk];
            bf16x8 bv_ = *(const bf16x8*)&sWv[rowb * BK + fk];
#pragma unroll
            for (int mi = 0; mi < 4; ++mi) {
                accM[mi][ni] = __builtin_amdgcn_mfma_f32_16x16x32_bf16(
                    ax[mi], bm_, accM[mi][ni], 0, 0, 0);
                accV[mi][ni] = __builtin_amdgcn_mfma_f32_16x16x32_bf16(
                    ax2[mi], bv_, accV[mi][ni], 0, 0, 0);
            }
        }
    }

    // ---- epilogue: C/D layout col = lane&15, row = (lane>>4)*4 + r
    const int oc = lane & 15;
    const int orb = (lane >> 4) << 2;
#pragma unroll
    for (int mi = 0; mi < 4; ++mi) {
#pragma unroll
        for (int ni = 0; ni < 4; ++ni) {
            const int gn = bn + n0 + ni * 16 + oc;
            const int gm = bm + m0 + mi * 16 + orb;
#pragma unroll
            for (int r = 0; r < 4; ++r) {
                const size_t off = (size_t)(gm + r) * O_DIM + gn;
                const float mu = accM[mi][ni][r];
                const float vv = accV[mi][ni][r];
                out[off] = fmaf(sqrtf(fmaxf(vv, 1e-8f)), eps[off], mu);
            }
        }
    }
}

// ---------------------------------------------------------------------------
extern "C" void kernel_launch(void* const* d_in, const int* in_sizes, int n_in,
                              void* d_out, int out_size, void* d_ws, size_t ws_size,
                              hipStream_t stream) {
    const float* x   = (const float*)d_in[0];
    const float* tn  = (const float*)d_in[1];
    const float* tp  = (const float*)d_in[2];
    const float* sc  = (const float*)d_in[3];
    const float* eps = (const float*)d_in[4];
    float* out = (float*)d_out;

    const size_t NE = (size_t)O_DIM * I_DIM;   // 16.7M, same for x
    unsigned short* xb  = (unsigned short*)d_ws;
    unsigned short* x2b = xb + NE;
    unsigned short* wm  = x2b + NE;
    unsigned short* wv  = wm + NE;
    // ws usage: 4 * 32 MB = 128 MB bf16 scratch

    const int pblocks = (int)(NE / 4 / 256);   // 16384
    prep_x<<<pblocks, 256, 0, stream>>>((const float4*)x, (ushort4*)xb, (ushort4*)x2b);
    prep_weights<<<pblocks, 256, 0, stream>>>((const float4*)tn, (const float4*)tp,
                                              (const float4*)sc, (ushort4*)wm, (ushort4*)wv);

    dim3 grid(O_DIM / BN, B_DIM / BM);   // (32, 32)
    fused_dual_gemm<<<grid, 256, 0, stream>>>(
        (const bf16*)xb, (const bf16*)x2b, (const bf16*)wm, (const bf16*)wv, eps, out);
}

// Round 2
// 610.948 us; speedup vs baseline: 1.0479x; 1.0479x over previous
//
#include <hip/hip_runtime.h>

// Problem dims (LRNetLinear): out = B x O, x = B x I, weights O x I
#define I_DIM 4096
#define O_DIM 4096
#define B_DIM 4096

typedef __bf16 bf16;
typedef __attribute__((ext_vector_type(8))) __bf16 bf16x8;
typedef __attribute__((ext_vector_type(4))) float f32x4;
typedef __attribute__((ext_vector_type(8))) unsigned short ushort8;

// fp32 -> bf16 bits, round-to-nearest-even
__device__ inline unsigned short f2bf_bits(float f) {
    unsigned u = __builtin_bit_cast(unsigned, f);
    unsigned r = 0x7fffu + ((u >> 16) & 1u);
    return (unsigned short)((u + r) >> 16);
}

__device__ inline void lr_wmv(float tn, float tp, float s,
                              unsigned short& wm, unsigned short& wv) {
    float m = fmaxf(fmaxf(tn, tp), 0.0f);
    float en = __expf(tn - m);
    float ez = __expf(-m);
    float ep = __expf(tp - m);
    float inv = __builtin_amdgcn_rcpf(en + ez + ep);
    float pn = en * inv, pp = ep * inv;
    float d = pp - pn;
    wm = f2bf_bits(d * s);
    wv = f2bf_bits((pp + pn - d * d) * (s * s));
}

// ---------------------------------------------------------------------------
// Fused prep: blocks [0, nbx) convert x -> bf16(x), bf16(x^2)  (8 elems/thr),
// blocks [nbx, ...) convert weights -> bf16 w_mean, w_var      (4 elems/thr).
// ---------------------------------------------------------------------------
__global__ void prep_all(const float4* __restrict__ x,
                         ushort8* __restrict__ xb8, ushort8* __restrict__ x2b8,
                         const float4* __restrict__ tn, const float4* __restrict__ tp,
                         const float4* __restrict__ sc,
                         ushort4* __restrict__ wm, ushort4* __restrict__ wv,
                         int nbx) {
    const int bid = blockIdx.x;
    if (bid < nbx) {
        size_t i = (size_t)bid * blockDim.x + threadIdx.x;
        float4 a = x[2 * i];
        float4 b = x[2 * i + 1];
        ushort8 o1, o2;
        o1[0] = f2bf_bits(a.x); o1[1] = f2bf_bits(a.y);
        o1[2] = f2bf_bits(a.z); o1[3] = f2bf_bits(a.w);
        o1[4] = f2bf_bits(b.x); o1[5] = f2bf_bits(b.y);
        o1[6] = f2bf_bits(b.z); o1[7] = f2bf_bits(b.w);
        o2[0] = f2bf_bits(a.x * a.x); o2[1] = f2bf_bits(a.y * a.y);
        o2[2] = f2bf_bits(a.z * a.z); o2[3] = f2bf_bits(a.w * a.w);
        o2[4] = f2bf_bits(b.x * b.x); o2[5] = f2bf_bits(b.y * b.y);
        o2[6] = f2bf_bits(b.z * b.z); o2[7] = f2bf_bits(b.w * b.w);
        xb8[i] = o1;
        x2b8[i] = o2;
    } else {
        size_t i = (size_t)(bid - nbx) * blockDim.x + threadIdx.x;
        float4 a = tn[i];
        float4 b = tp[i];
        float4 s = sc[i];
        ushort4 om, ov;
        lr_wmv(a.x, b.x, s.x, om.x, ov.x);
        lr_wmv(a.y, b.y, s.y, om.y, ov.y);
        lr_wmv(a.z, b.z, s.z, om.z, ov.z);
        lr_wmv(a.w, b.w, s.w, om.w, ov.w);
        wm[i] = om;
        wv[i] = ov;
    }
}

// ---------------------------------------------------------------------------
// Fused dual GEMM, BK=64, XOR-swizzled LDS (conflict-free b128 reads).
// LDS layout per array: [128 rows][8 granules of 16B]; logical granule
// (row, cg) stored at granule row*8 + (cg ^ (row & 7)). Swizzle is applied
// on the *global* source address at staging time (global_load_lds writes
// wave-uniform base + lane*16), and on the LDS read address at fragment time.
// ---------------------------------------------------------------------------
#define BM 128
#define BN 128
#define BK 64

__device__ inline void gl_lds16(const bf16* g, bf16* l) {
    __builtin_amdgcn_global_load_lds(
        (const __attribute__((address_space(1))) unsigned int*)g,
        (__attribute__((address_space(3))) unsigned int*)l,
        16, 0, 0);
}

__global__ __launch_bounds__(256, 2)
void fused_dual_gemm(const bf16* __restrict__ Xb, const bf16* __restrict__ X2b,
                     const bf16* __restrict__ Wm, const bf16* __restrict__ Wv,
                     const float* __restrict__ eps, float* __restrict__ out) {
    __shared__ bf16 sX[BM * BK];
    __shared__ bf16 sX2[BM * BK];
    __shared__ bf16 sWm[BN * BK];
    __shared__ bf16 sWv[BN * BK];

    const int tid  = threadIdx.x;
    const int lane = tid & 63;
    const int wave = tid >> 6;

    const int bm = blockIdx.y * BM;
    const int bn = blockIdx.x * BN;

    // ---- staging mapping: each array = 16 KB = 16 chunks of 1 KB
    // (64 lanes x 16 B). Wave w stages chunks {w, w+4, w+8, w+12}.
    // Chunk c covers rows c*8 .. c*8+7. Lane: rowoff = lane>>3 (= row&7),
    // stored granule col = lane&7, so logical cg = (lane&7) ^ rowoff.
    const int rowoff = lane >> 3;
    const int cgoff  = ((lane & 7) ^ rowoff) << 3;   // elems within row

    const bf16* gX[4]; const bf16* gX2[4]; const bf16* gWm[4]; const bf16* gWv[4];
    int ldsoff[4];
#pragma unroll
    for (int j = 0; j < 4; ++j) {
        const int c = wave + 4 * j;
        const size_t ra = (size_t)(bm + c * 8 + rowoff) * I_DIM + cgoff;
        const size_t rb = (size_t)(bn + c * 8 + rowoff) * I_DIM + cgoff;
        gX[j]  = Xb  + ra;
        gX2[j] = X2b + ra;
        gWm[j] = Wm  + rb;
        gWv[j] = Wv  + rb;
        ldsoff[j] = c << 9;   // c * 512 elems (1 KB)
    }

    // ---- fragment read offsets (16x16x32: row = lane&15, k = (lane>>4)*8)
    const int fr  = lane & 15;
    const int cg0 = lane >> 4;                 // k-granule 0..3 (khalf 0)
    const int sw0 = (cg0 ^ (fr & 7)) << 3;     // swizzled elem col, khalf 0
    const int m0 = (wave >> 1) << 6;
    const int n0 = (wave & 1) << 6;

    f32x4 accM[4][4];
    f32x4 accV[4][4];
    const f32x4 z = {0.0f, 0.0f, 0.0f, 0.0f};
#pragma unroll
    for (int mi = 0; mi < 4; ++mi)
#pragma unroll
        for (int ni = 0; ni < 4; ++ni) { accM[mi][ni] = z; accV[mi][ni] = z; }

    for (int k0 = 0; k0 < I_DIM; k0 += BK) {
        __syncthreads();   // previous iteration's reads done before overwrite
#pragma unroll
        for (int j = 0; j < 4; ++j) {
            gl_lds16(gX[j]  + k0, sX  + ldsoff[j]);
            gl_lds16(gX2[j] + k0, sX2 + ldsoff[j]);
            gl_lds16(gWm[j] + k0, sWm + ldsoff[j]);
            gl_lds16(gWv[j] + k0, sWv + ldsoff[j]);
        }
        __syncthreads();   // staging complete (compiler drains vmcnt)

#pragma unroll
        for (int kh = 0; kh < 2; ++kh) {
            const int sw = sw0 ^ (kh << 5);    // khalf1: cg += 4 -> ^32 elems
            bf16x8 ax[4], ax2[4];
#pragma unroll
            for (int mi = 0; mi < 4; ++mi) {
                const int row = m0 + mi * 16 + fr;
                ax[mi]  = *(const bf16x8*)&sX [row * BK + sw];
                ax2[mi] = *(const bf16x8*)&sX2[row * BK + sw];
            }
#pragma unroll
            for (int ni = 0; ni < 4; ++ni) {
                const int rowb = n0 + ni * 16 + fr;
                bf16x8 bm_ = *(const bf16x8*)&sWm[rowb * BK + sw];
                bf16x8 bv_ = *(const bf16x8*)&sWv[rowb * BK + sw];
#pragma unroll
                for (int mi = 0; mi < 4; ++mi) {
                    accM[mi][ni] = __builtin_amdgcn_mfma_f32_16x16x32_bf16(
                        ax[mi], bm_, accM[mi][ni], 0, 0, 0);
                    accV[mi][ni] = __builtin_amdgcn_mfma_f32_16x16x32_bf16(
                        ax2[mi], bv_, accV[mi][ni], 0, 0, 0);
                }
            }
        }
    }

    // ---- epilogue: C/D layout col = lane&15, row = (lane>>4)*4 + r
    const int oc  = lane & 15;
    const int orb = (lane >> 4) << 2;
#pragma unroll
    for (int mi = 0; mi < 4; ++mi) {
#pragma unroll
        for (int ni = 0; ni < 4; ++ni) {
            const int gn = bn + n0 + ni * 16 + oc;
            const int gm = bm + m0 + mi * 16 + orb;
#pragma unroll
            for (int r = 0; r < 4; ++r) {
                const size_t off = (size_t)(gm + r) * O_DIM + gn;
                const float mu = accM[mi][ni][r];
                const float vv = accV[mi][ni][r];
                out[off] = fmaf(sqrtf(fmaxf(vv, 1e-8f)), eps[off], mu);
            }
        }
    }
}

// ---------------------------------------------------------------------------
extern "C" void kernel_launch(void* const* d_in, const int* in_sizes, int n_in,
                              void* d_out, int out_size, void* d_ws, size_t ws_size,
                              hipStream_t stream) {
    const float* x   = (const float*)d_in[0];
    const float* tn  = (const float*)d_in[1];
    const float* tp  = (const float*)d_in[2];
    const float* sc  = (const float*)d_in[3];
    const float* eps = (const float*)d_in[4];
    float* out = (float*)d_out;

    const size_t NE = (size_t)O_DIM * I_DIM;   // 16.7M
    unsigned short* xb  = (unsigned short*)d_ws;
    unsigned short* x2b = xb + NE;
    unsigned short* wm  = x2b + NE;
    unsigned short* wv  = wm + NE;

    const int nbx = (int)(NE / 8 / 256);       // 8192  (x path, 8 elems/thr)
    const int nbw = (int)(NE / 4 / 256);       // 16384 (weight path)
    prep_all<<<nbx + nbw, 256, 0, stream>>>(
        (const float4*)x, (ushort8*)xb, (ushort8*)x2b,
        (const float4*)tn, (const float4*)tp, (const float4*)sc,
        (ushort4*)wm, (ushort4*)wv, nbx);

    dim3 grid(O_DIM / BN, B_DIM / BM);   // (32, 32)
    fused_dual_gemm<<<grid, 256, 0, stream>>>(
        (const bf16*)xb, (const bf16*)x2b, (const bf16*)wm, (const bf16*)wv, eps, out);
}